// Round 11
// baseline (606.042 us; speedup 1.0000x reference)
//
#include <hip/hip_runtime.h>
#include <cstddef>
#include <cstdint>

// ---------------- problem constants ----------------
#define ALPHA_C 7.7550531393693407f   // -log(0.001/7*3)
constexpr int BB = 2;      // batch
constexpr int LL = 2048;   // seq len
constexpr int HH = 8;      // heads
constexpr size_t OUT0  = (size_t)BB * LL * 512;          // output 0 floats
constexpr size_t PLANE = (size_t)BB * HH * LL * 64;      // per-head-major plane elems
constexpr size_t XN    = (size_t)BB * LL * 512;          // X plane elems (4096x512)
constexpr size_t WN    = (size_t)512 * 512;              // W plane elems
constexpr size_t UN    = (size_t)16 * 32 * 32 * 4096;    // u-cache elems (bf16)

typedef __attribute__((ext_vector_type(8))) short bf16x8;
typedef __attribute__((ext_vector_type(4))) short short4v;
typedef __attribute__((ext_vector_type(4))) float f32x4;

__device__ inline short f2bf(float x) {
  union { float f; unsigned u; } un; un.f = x;
  unsigned r = un.u + 0x7fffu + ((un.u >> 16) & 1u);   // RNE
  return (short)(r >> 16);
}
__device__ inline float bf2f(short s) {
  union { unsigned u; float f; } un; un.u = ((unsigned)(unsigned short)s) << 16;
  return un.f;
}
// 3-way bf16 split: x ~= h + m + l (~24 mantissa bits)
__device__ inline void split3(float x, short& h, short& m, short& l) {
  h = f2bf(x); float r = x - bf2f(h);
  m = f2bf(r); float r2 = r - bf2f(m);
  l = f2bf(r2);
}

// ---------------- K0: elementwise split3 into bf16 planes (x3 tensors) --------
__global__ __launch_bounds__(256) void k_split3x(
    const float* __restrict__ a, const float* __restrict__ b, const float* __restrict__ c,
    short* __restrict__ da, short* __restrict__ db, short* __restrict__ dc, size_t n)
{
  size_t i = ((size_t)blockIdx.x * 256 + threadIdx.x) * 4;
  if (i >= n) return;
  const float* srcs[3] = {a, b, c};
  short* dsts[3] = {da, db, dc};
  #pragma unroll
  for (int s = 0; s < 3; ++s) {
    float4 x = *(const float4*)&srcs[s][i];
    short4v h, m, l;
    short th, tm, tl;
    split3(x.x, th, tm, tl); h[0] = th; m[0] = tm; l[0] = tl;
    split3(x.y, th, tm, tl); h[1] = th; m[1] = tm; l[1] = tl;
    split3(x.z, th, tm, tl); h[2] = th; m[2] = tm; l[2] = tl;
    split3(x.w, th, tm, tl); h[3] = th; m[3] = tm; l[3] = tl;
    *(short4v*)&dsts[s][i]         = h;
    *(short4v*)&dsts[s][n + i]     = m;
    *(short4v*)&dsts[s][2 * n + i] = l;
  }
}

// ---------------- K0c: fp32 -> bf16 convert (w_fc) ----------------
__global__ __launch_bounds__(256) void k_cvtbf(
    const float* __restrict__ src, short* __restrict__ dst, size_t n)
{
  size_t i = ((size_t)blockIdx.x * 256 + threadIdx.x) * 8;
  if (i >= n) return;
  float4 a = *(const float4*)&src[i];
  float4 b = *(const float4*)&src[i + 4];
  bf16x8 o;
  o[0] = f2bf(a.x); o[1] = f2bf(a.y); o[2] = f2bf(a.z); o[3] = f2bf(a.w);
  o[4] = f2bf(b.x); o[5] = f2bf(b.y); o[6] = f2bf(b.z); o[7] = f2bf(b.w);
  *(bf16x8*)&dst[i] = o;
}

// ---------------- K0b: 3-tap avg-pool of V^T along l (zero-padded) ----------------
__global__ __launch_bounds__(256) void k_vavg(
    const short* __restrict__ vt, short* __restrict__ vavgt)
{
  const size_t row = blockIdx.x;           // 1024 rows of LL
  const short* src = vt + row * LL;
  short* dst = vavgt + row * LL;
  const int c0 = threadIdx.x * 8;
  bf16x8 x = *(const bf16x8*)&src[c0];
  float xf[10];
  xf[0] = (c0 > 0) ? bf2f(src[c0 - 1]) : 0.f;
  #pragma unroll
  for (int i = 0; i < 8; ++i) xf[i + 1] = bf2f(x[i]);
  xf[9] = (c0 + 8 < LL) ? bf2f(src[c0 + 8]) : 0.f;
  bf16x8 o;
  #pragma unroll
  for (int i = 0; i < 8; ++i) o[i] = f2bf((xf[i] + xf[i + 1] + xf[i + 2]) * (1.0f / 3.0f));
  *(bf16x8*)&dst[c0] = o;
}

// ---------------- K1: QKV projection — 6-term split bf16 MFMA ----------------
__global__ __launch_bounds__(256) void k_proj(
    const short* __restrict__ xq, const short* __restrict__ xk, const short* __restrict__ xv,
    const short* __restrict__ wq3, const short* __restrict__ wk3, const short* __restrict__ wv3,
    short* __restrict__ qs, short* __restrict__ ks, short* __restrict__ vt)
{
  const int bx  = blockIdx.x;
  const int sel = bx >> 3;
  const int n0  = (bx & 7) * 64;
  const int m0  = blockIdx.y * 64;
  const short* X = sel == 0 ? xq  : (sel == 1 ? xk  : xv);
  const short* W = sel == 0 ? wq3 : (sel == 1 ? wk3 : wv3);

  __shared__ short Xs[3][64 * 72];
  __shared__ short Ws[3][64 * 72];
  const int tid = threadIdx.x;
  const int lane = tid & 63, w = tid >> 6;
  const int quad = lane >> 4, l15 = lane & 15, colg = l15;
  const int sr8 = tid >> 3, sc8 = (tid & 7) * 8;

  f32x4 acc[4];
  #pragma unroll
  for (int t = 0; t < 4; ++t) { acc[t][0]=0.f; acc[t][1]=0.f; acc[t][2]=0.f; acc[t][3]=0.f; }

  for (int kt = 0; kt < 8; ++kt) {
    const int k0 = kt * 64;
    #pragma unroll
    for (int p = 0; p < 3; ++p) {
      #pragma unroll
      for (int it = 0; it < 2; ++it) {
        int r = it * 32 + sr8;
        *(bf16x8*)&Xs[p][r * 72 + sc8] = *(const bf16x8*)&X[p * XN + (size_t)(m0 + r) * 512 + k0 + sc8];
        *(bf16x8*)&Ws[p][r * 72 + sc8] = *(const bf16x8*)&W[p * WN + (size_t)(n0 + r) * 512 + k0 + sc8];
      }
    }
    __syncthreads();
    #pragma unroll
    for (int ch = 0; ch < 2; ++ch) {
      const int ka = (quad << 3) + ch * 32;
      const int ar = (w * 16 + l15) * 72 + ka;
      bf16x8 ah = *(const bf16x8*)&Xs[0][ar];
      bf16x8 am = *(const bf16x8*)&Xs[1][ar];
      bf16x8 al = *(const bf16x8*)&Xs[2][ar];
      #pragma unroll
      for (int t = 0; t < 4; ++t) {
        const int br = (t * 16 + l15) * 72 + ka;
        bf16x8 bh_ = *(const bf16x8*)&Ws[0][br];
        bf16x8 bm_ = *(const bf16x8*)&Ws[1][br];
        bf16x8 bl_ = *(const bf16x8*)&Ws[2][br];
        acc[t] = __builtin_amdgcn_mfma_f32_16x16x32_bf16(ah, bh_, acc[t], 0, 0, 0);
        acc[t] = __builtin_amdgcn_mfma_f32_16x16x32_bf16(ah, bm_, acc[t], 0, 0, 0);
        acc[t] = __builtin_amdgcn_mfma_f32_16x16x32_bf16(am, bh_, acc[t], 0, 0, 0);
        acc[t] = __builtin_amdgcn_mfma_f32_16x16x32_bf16(ah, bl_, acc[t], 0, 0, 0);
        acc[t] = __builtin_amdgcn_mfma_f32_16x16x32_bf16(al, bh_, acc[t], 0, 0, 0);
        acc[t] = __builtin_amdgcn_mfma_f32_16x16x32_bf16(am, bm_, acc[t], 0, 0, 0);
      }
    }
    __syncthreads();
  }

  if (sel < 2) {
    short* Y = sel == 0 ? qs : ks;
    #pragma unroll
    for (int t = 0; t < 4; ++t) {
      const int e = n0 + t * 16 + colg, h = e >> 6, dk = e & 63;
      #pragma unroll
      for (int r = 0; r < 4; ++r) {
        const int m = m0 + w * 16 + quad * 4 + r;
        const int b = m >> 11, l = m & 2047;
        size_t base = ((size_t)(b * HH + h) * LL + l) * 64 + dk;
        short hh, mm, ll; split3(acc[t][r], hh, mm, ll);
        Y[base] = hh; Y[PLANE + base] = mm; Y[2 * PLANE + base] = ll;
      }
    }
  } else {
    const int b  = m0 >> 11;
    const int l0 = (m0 & 2047) + w * 16 + quad * 4;
    #pragma unroll
    for (int t = 0; t < 4; ++t) {
      const int e = n0 + t * 16 + colg, h = e >> 6, dk = e & 63;
      short4v s;
      #pragma unroll
      for (int r = 0; r < 4; ++r) s[r] = f2bf(acc[t][r]);
      *(short4v*)&vt[(((size_t)b * HH + h) * 64 + dk) * LL + l0] = s;
    }
  }
}

// ---------------- K2: single-pass flash — QK -> u-cache + stats + online PV --------
// grid (32 i-tiles of 64 rows, 16 bh). Writes u (bf16), mstats, rowstats, outh (bf16).
// PV uses pre-pooled Vavg (pool(p)@V == p@pool(V)); V B-frags load global->reg (L2-hot).
__global__ __launch_bounds__(256) void k_flash(
    const short* __restrict__ qs, const short* __restrict__ ks,
    const short* __restrict__ vavgt,
    short* __restrict__ u_g, float* __restrict__ mstats, float* __restrict__ rowstats,
    short* __restrict__ outh)
{
  const int i0 = blockIdx.x * 64;
  const int bh = blockIdx.y;
  const int b = bh >> 3, h = bh & 7;
  __shared__ short Ks[3][64 * 72];   // 27.6 KB
  __shared__ short Us[64 * 72];      // 9.2 KB
  const int tid = threadIdx.x;
  const int lane = tid & 63, w = tid >> 6;
  const int quad = lane >> 4, colg = lane & 15, l15 = lane & 15;
  const int sr8 = tid >> 3, sc8 = (tid & 7) * 8;

  bf16x8 qf[3][2];
  {
    const size_t qoff = ((size_t)bh * LL + i0 + w * 16 + l15) * 64 + (quad << 3);
    #pragma unroll
    for (int p = 0; p < 3; ++p)
      #pragma unroll
      for (int ch = 0; ch < 2; ++ch)
        qf[p][ch] = *(const bf16x8*)&qs[p * PLANE + qoff + ch * 32];
  }

  // prestage K(0)
  const short* kbase = ks + (size_t)bh * LL * 64;
  const short* Vt = vavgt + (size_t)bh * 64 * LL;
  #pragma unroll
  for (int p = 0; p < 3; ++p)
    #pragma unroll
    for (int it = 0; it < 2; ++it) {
      int r = it * 32 + sr8;
      *(bf16x8*)&Ks[p][r * 72 + sc8] = *(const bf16x8*)&kbase[p * PLANE + (size_t)r * 64 + sc8];
    }
  __syncthreads();

  float M[4], S[4];
  #pragma unroll
  for (int r = 0; r < 4; ++r) { M[r] = -3.0e38f; S[r] = 0.f; }
  f32x4 pv[4];
  #pragma unroll
  for (int t = 0; t < 4; ++t) { pv[t][0]=0.f; pv[t][1]=0.f; pv[t][2]=0.f; pv[t][3]=0.f; }

  for (int jt = 0; jt < 32; ++jt) {
    const int j0 = jt * 64;
    // register prefetch: K(jt+1) and Vavg(jt) B-frags
    bf16x8 kreg[3][2];
    if (jt + 1 < 32) {
      #pragma unroll
      for (int p = 0; p < 3; ++p)
        #pragma unroll
        for (int it = 0; it < 2; ++it) {
          int r = it * 32 + sr8;
          kreg[p][it] = *(const bf16x8*)&kbase[p * PLANE + ((size_t)(jt + 1) * 64 + r) * 64 + sc8];
        }
    }
    bf16x8 vfrag[4][2];
    #pragma unroll
    for (int t = 0; t < 4; ++t)
      #pragma unroll
      for (int ch = 0; ch < 2; ++ch)
        vfrag[t][ch] = *(const bf16x8*)&Vt[(size_t)(t * 16 + l15) * LL + j0 + (quad << 3) + ch * 32];

    f32x4 acc[4];
    #pragma unroll
    for (int t = 0; t < 4; ++t) { acc[t][0]=0.f; acc[t][1]=0.f; acc[t][2]=0.f; acc[t][3]=0.f; }
    #pragma unroll
    for (int ch = 0; ch < 2; ++ch) {
      const int ka = (quad << 3) + ch * 32;
      #pragma unroll
      for (int t = 0; t < 4; ++t) {
        const int br = (t * 16 + l15) * 72 + ka;
        bf16x8 bh_ = *(const bf16x8*)&Ks[0][br];
        bf16x8 bm_ = *(const bf16x8*)&Ks[1][br];
        bf16x8 bl_ = *(const bf16x8*)&Ks[2][br];
        acc[t] = __builtin_amdgcn_mfma_f32_16x16x32_bf16(qf[0][ch], bh_, acc[t], 0, 0, 0);
        acc[t] = __builtin_amdgcn_mfma_f32_16x16x32_bf16(qf[0][ch], bm_, acc[t], 0, 0, 0);
        acc[t] = __builtin_amdgcn_mfma_f32_16x16x32_bf16(qf[1][ch], bh_, acc[t], 0, 0, 0);
        acc[t] = __builtin_amdgcn_mfma_f32_16x16x32_bf16(qf[0][ch], bl_, acc[t], 0, 0, 0);
        acc[t] = __builtin_amdgcn_mfma_f32_16x16x32_bf16(qf[2][ch], bh_, acc[t], 0, 0, 0);
        acc[t] = __builtin_amdgcn_mfma_f32_16x16x32_bf16(qf[1][ch], bm_, acc[t], 0, 0, 0);
      }
    }

    // tile max (16-lane shuffle), u = exp(e - mx) -> Us, online (M,S), save alpha/beta
    float alf[4], bet[4];
    #pragma unroll
    for (int r = 0; r < 4; ++r) {
      const int row = w * 16 + quad * 4 + r;
      const int irow = i0 + row;
      float e0 = -ALPHA_C * (float)(j0 +  0 + colg - irow) * (acc[0][r] * 0.125f);
      float e1 = -ALPHA_C * (float)(j0 + 16 + colg - irow) * (acc[1][r] * 0.125f);
      float e2 = -ALPHA_C * (float)(j0 + 32 + colg - irow) * (acc[2][r] * 0.125f);
      float e3 = -ALPHA_C * (float)(j0 + 48 + colg - irow) * (acc[3][r] * 0.125f);
      float mx = fmaxf(fmaxf(e0, e1), fmaxf(e2, e3));
      #pragma unroll
      for (int d = 1; d < 16; d <<= 1) mx = fmaxf(mx, __shfl_xor(mx, d));
      float u0 = __expf(e0 - mx), u1 = __expf(e1 - mx);
      float u2 = __expf(e2 - mx), u3 = __expf(e3 - mx);
      float s = u0 + u1 + u2 + u3;
      #pragma unroll
      for (int d = 1; d < 16; d <<= 1) s += __shfl_xor(s, d);
      float nM = fmaxf(M[r], mx);
      alf[r] = __expf(M[r] - nM);
      bet[r] = __expf(mx - nM);
      S[r] = S[r] * alf[r] + s * bet[r];
      M[r] = nM;
      Us[row * 72 +  0 + colg] = f2bf(u0);
      Us[row * 72 + 16 + colg] = f2bf(u1);
      Us[row * 72 + 32 + colg] = f2bf(u2);
      Us[row * 72 + 48 + colg] = f2bf(u3);
      if (colg == 0) mstats[((size_t)bh * 32 + jt) * LL + irow] = mx;
    }
    __syncthreads();   // Us complete; Ks consumed

    // PV: tmp = u @ Vavg(jt); pv = pv*alpha + tmp*beta
    {
      f32x4 tmp[4];
      #pragma unroll
      for (int t = 0; t < 4; ++t) { tmp[t][0]=0.f; tmp[t][1]=0.f; tmp[t][2]=0.f; tmp[t][3]=0.f; }
      #pragma unroll
      for (int ch = 0; ch < 2; ++ch) {
        bf16x8 af = *(const bf16x8*)&Us[(w * 16 + l15) * 72 + (quad << 3) + ch * 32];
        #pragma unroll
        for (int t = 0; t < 4; ++t)
          tmp[t] = __builtin_amdgcn_mfma_f32_16x16x32_bf16(af, vfrag[t][ch], tmp[t], 0, 0, 0);
      }
      #pragma unroll
      for (int t = 0; t < 4; ++t)
        #pragma unroll
        for (int r = 0; r < 4; ++r)
          pv[t][r] = pv[t][r] * alf[r] + tmp[t][r] * bet[r];
    }

    // restage K, store u-cache
    if (jt + 1 < 32) {
      #pragma unroll
      for (int p = 0; p < 3; ++p)
        #pragma unroll
        for (int it = 0; it < 2; ++it) {
          int r = it * 32 + sr8;
          *(bf16x8*)&Ks[p][r * 72 + sc8] = kreg[p][it];
        }
    }
    {
      const size_t ubase = (((size_t)bh * 32 + blockIdx.x) * 32 + jt) * 4096;
      #pragma unroll
      for (int it = 0; it < 2; ++it) {
        int rr = it * 32 + sr8;
        bf16x8 uu = *(const bf16x8*)&Us[rr * 72 + sc8];
        *(bf16x8*)&u_g[ubase + (size_t)rr * 64 + sc8] = uu;
      }
    }
    __syncthreads();
  }

  if (colg == 0) {
    #pragma unroll
    for (int r = 0; r < 4; ++r) {
      int irow = i0 + w * 16 + quad * 4 + r;
      size_t idx = ((size_t)bh * LL + irow) * 2;
      rowstats[idx] = M[r]; rowstats[idx + 1] = S[r];
    }
  }
  // epilogue: pv /= S -> bf16 outh
  #pragma unroll
  for (int t = 0; t < 4; ++t)
    #pragma unroll
    for (int r = 0; r < 4; ++r) {
      int i = i0 + w * 16 + quad * 4 + r;
      int d = t * 16 + colg;
      outh[((size_t)b * LL + i) * 512 + h * 64 + d] = f2bf(pv[t][r] / S[r]);
    }
}

// ---------------- K3: pooled writer — u-cache -> p -> 3-tap pool -> pooled (fp32) ------
// grid (32 i-tiles of 64 rows, 16 bh). Pure memory: no MFMA, no K/V.
__global__ __launch_bounds__(256) void k_poolw(
    const short* __restrict__ u_g, const float* __restrict__ mstats,
    const float* __restrict__ rowstats, float* __restrict__ pooled)
{
  const int i0 = blockIdx.x * 64, ib = blockIdx.x;
  const int bh = blockIdx.y;
  float* Pg = pooled + (size_t)bh * LL * LL;

  __shared__ short Pa[2][64 * 72];     // 18.4 KB p (bf16), 2-slot
  __shared__ float lhalo[64];

  const int tid = threadIdx.x;
  const int w = tid >> 6;
  const int sr8 = tid >> 3, sc8 = (tid & 7) * 8;

  const int r0 = sr8, r1 = sr8 + 32;
  float M0, iS0, M1, iS1;
  {
    float2 a = *(const float2*)&rowstats[((size_t)bh * LL + i0 + r0) * 2];
    float2 c = *(const float2*)&rowstats[((size_t)bh * LL + i0 + r1) * 2];
    M0 = a.x; iS0 = 1.0f / a.y; M1 = c.x; iS1 = 1.0f / c.y;
  }
  if (tid < 64) lhalo[tid] = 0.f;
  __syncthreads();

  for (int jt = 0; jt <= 32; ++jt) {
    // phase A: load u(jt), rescale -> Pa[jt&1]
    if (jt < 32) {
      const size_t ubase = (((size_t)bh * 32 + ib) * 32 + jt) * 4096;
      const float* mst = &mstats[((size_t)bh * 32 + jt) * LL + i0];
      float c0 = __expf(mst[r0] - M0) * iS0;
      float c1 = __expf(mst[r1] - M1) * iS1;
      bf16x8 u0 = *(const bf16x8*)&u_g[ubase + (size_t)r0 * 64 + sc8];
      bf16x8 u1 = *(const bf16x8*)&u_g[ubase + (size_t)r1 * 64 + sc8];
      bf16x8 p0, p1;
      #pragma unroll
      for (int i = 0; i < 8; ++i) {
        p0[i] = f2bf(bf2f(u0[i]) * c0);
        p1[i] = f2bf(bf2f(u1[i]) * c1);
      }
      *(bf16x8*)&Pa[jt & 1][r0 * 72 + sc8] = p0;
      *(bf16x8*)&Pa[jt & 1][r1 * 72 + sc8] = p1;
    }
    __syncthreads();

    // phase B: pool(jt-1), nontemporal write
    if (jt >= 1) {
      const short* Pp = Pa[(jt - 1) & 1];
      const short* Pn = Pa[jt & 1];
      #pragma unroll
      for (int u = 0; u < 2; ++u) {
        const int row = (u == 0) ? r0 : r1;
        const int c0 = sc8;
        bf16x8 x = *(const bf16x8*)&Pp[row * 72 + c0];
        float xf[8];
        #pragma unroll
        for (int i = 0; i < 8; ++i) xf[i] = bf2f(x[i]);
        float lft = (c0 == 0)  ? lhalo[row] : bf2f(Pp[row * 72 + c0 - 1]);
        float rgt = (c0 == 56) ? ((jt < 32) ? bf2f(Pn[row * 72]) : 0.f)
                               : bf2f(Pp[row * 72 + c0 + 8]);
        f32x4 o0, o1;
        o0[0] = (lft   + xf[0] + xf[1]) * (1.0f/3.0f);
        o0[1] = (xf[0] + xf[1] + xf[2]) * (1.0f/3.0f);
        o0[2] = (xf[1] + xf[2] + xf[3]) * (1.0f/3.0f);
        o0[3] = (xf[2] + xf[3] + xf[4]) * (1.0f/3.0f);
        o1[0] = (xf[3] + xf[4] + xf[5]) * (1.0f/3.0f);
        o1[1] = (xf[4] + xf[5] + xf[6]) * (1.0f/3.0f);
        o1[2] = (xf[5] + xf[6] + xf[7]) * (1.0f/3.0f);
        o1[3] = (xf[6] + xf[7] + rgt  ) * (1.0f/3.0f);
        float* dst = &Pg[(size_t)(i0 + row) * LL + (jt - 1) * 64 + c0];
        __builtin_nontemporal_store(o0, (f32x4*)dst);
        __builtin_nontemporal_store(o1, (f32x4*)(dst + 4));
        if (c0 == 56) lhalo[row] = xf[7];
      }
    }
    __syncthreads();
  }
  (void)w;
}

// ---------------- K4: fc = out_h @ w_fc^T  (pure bf16 MFMA, copy staging) ----------
__global__ __launch_bounds__(256) void k_fc(
    const short* __restrict__ outh, const short* __restrict__ wfcb, float* __restrict__ fcout)
{
  const int n0 = blockIdx.x * 64;
  const int m0 = blockIdx.y * 64;
  __shared__ short Asm[64 * 72];
  __shared__ short Bsm[64 * 72];
  const int tid = threadIdx.x;
  const int lane = tid & 63, w = tid >> 6;
  const int sr8 = tid >> 3, sc8 = (tid & 7) * 8;

  f32x4 acc[4];
  #pragma unroll
  for (int t = 0; t < 4; ++t) { acc[t][0]=0.f; acc[t][1]=0.f; acc[t][2]=0.f; acc[t][3]=0.f; }

  for (int k0 = 0; k0 < 512; k0 += 64) {
    #pragma unroll
    for (int it = 0; it < 2; ++it) {
      int r = it * 32 + sr8;
      *(bf16x8*)&Asm[r * 72 + sc8] = *(const bf16x8*)&outh[(size_t)(m0 + r) * 512 + k0 + sc8];
      *(bf16x8*)&Bsm[r * 72 + sc8] = *(const bf16x8*)&wfcb[(size_t)(n0 + r) * 512 + k0 + sc8];
    }
    __syncthreads();
    #pragma unroll
    for (int ch = 0; ch < 2; ++ch) {
      const int ka = ((lane >> 4) << 3) + ch * 32;
      bf16x8 af = *(const bf16x8*)&Asm[(w * 16 + (lane & 15)) * 72 + ka];
      #pragma unroll
      for (int t = 0; t < 4; ++t) {
        bf16x8 bfv = *(const bf16x8*)&Bsm[(t * 16 + (lane & 15)) * 72 + ka];
        acc[t] = __builtin_amdgcn_mfma_f32_16x16x32_bf16(af, bfv, acc[t], 0, 0, 0);
      }
    }
    __syncthreads();
  }
  const int q4 = lane >> 4, colg = lane & 15;
  #pragma unroll
  for (int t = 0; t < 4; ++t)
    #pragma unroll
    for (int r = 0; r < 4; ++r) {
      int m = m0 + w * 16 + q4 * 4 + r;
      fcout[(size_t)m * 512 + n0 + t * 16 + colg] = acc[t][r];
    }
}

// ---------------- K5: residual + LayerNorm ----------------
__global__ __launch_bounds__(256) void k_ln(
    const float* __restrict__ fcout, const float* __restrict__ resid,
    const float* __restrict__ gamma, const float* __restrict__ beta,
    float* __restrict__ out)
{
  const size_t row = blockIdx.x;
  const int tid = threadIdx.x;
  __shared__ float red[256];

  float x0 = fcout[row * 512 + tid]       + resid[row * 512 + tid];
  float x1 = fcout[row * 512 + 256 + tid] + resid[row * 512 + 256 + tid];

  red[tid] = x0 + x1; __syncthreads();
  for (int off = 128; off > 0; off >>= 1) {
    if (tid < off) red[tid] += red[tid + off];
    __syncthreads();
  }
  const float mu = red[0] * (1.0f / 512.0f); __syncthreads();

  float d0 = x0 - mu, d1 = x1 - mu;
  red[tid] = d0 * d0 + d1 * d1; __syncthreads();
  for (int off = 128; off > 0; off >>= 1) {
    if (tid < off) red[tid] += red[tid + off];
    __syncthreads();
  }
  const float var = red[0] * (1.0f / 512.0f);
  const float rstd = 1.0f / sqrtf(var + 1e-6f);

  out[row * 512 + tid]       = d0 * rstd * gamma[tid]       + beta[tid];
  out[row * 512 + 256 + tid] = d1 * rstd * gamma[tid + 256] + beta[tid + 256];
}

// ---------------- launch ----------------
extern "C" void kernel_launch(void* const* d_in, const int* in_sizes, int n_in,
                              void* d_out, int out_size, void* d_ws, size_t ws_size,
                              hipStream_t stream)
{
  const float* q     = (const float*)d_in[0];
  const float* k     = (const float*)d_in[1];
  const float* v     = (const float*)d_in[2];
  const float* wq    = (const float*)d_in[3];
  const float* wk    = (const float*)d_in[4];
  const float* wv    = (const float*)d_in[5];
  const float* wfc   = (const float*)d_in[6];
  const float* gamma = (const float*)d_in[7];
  const float* beta  = (const float*)d_in[8];

  float* out    = (float*)d_out;
  float* pooled = out + OUT0;

  // workspace layout (~230 MB)
  short* xq    = (short*)d_ws;           // 3*XN each
  short* xk    = xq + 3 * XN;
  short* xv    = xk + 3 * XN;
  short* wq3   = xv + 3 * XN;            // 3*WN each
  short* wk3   = wq3 + 3 * WN;
  short* wv3   = wk3 + 3 * WN;
  short* qsp   = wv3 + 3 * WN;           // 3*PLANE
  short* ksp   = qsp + 3 * PLANE;        // 3*PLANE
  short* vt    = ksp + 3 * PLANE;        // PLANE (raw V^T)
  short* vavgt = vt + PLANE;             // PLANE (pooled V^T)
  short* wfcb  = vavgt + PLANE;          // WN bf16
  short* outh  = wfcb + WN;              // OUT0 bf16
  short* u_g   = outh + OUT0;            // UN bf16 (134 MB u-cache)
  float* mstats   = (float*)(u_g + UN);  // 16*32*2048 f32 (8 MB)
  float* rowstats = mstats + (size_t)16 * 32 * LL;   // 65536 f32
  float* fcout    = rowstats + 2 * (size_t)BB * HH * LL;  // OUT0 f32

  k_split3x<<<dim3((unsigned)(XN / 4 / 256)), 256, 0, stream>>>(q, k, v, xq, xk, xv, XN);
  k_split3x<<<dim3((unsigned)(WN / 4 / 256)), 256, 0, stream>>>(wq, wk, wv, wq3, wk3, wv3, WN);
  k_cvtbf  <<<dim3((unsigned)(WN / 8 / 256)), 256, 0, stream>>>(wfc, wfcb, WN);
  k_proj   <<<dim3(24, 64), 256, 0, stream>>>(xq, xk, xv, wq3, wk3, wv3, qsp, ksp, vt);
  k_vavg   <<<dim3(1024),   256, 0, stream>>>(vt, vavgt);
  k_flash  <<<dim3(32, 16), 256, 0, stream>>>(qsp, ksp, vavgt, u_g, mstats, rowstats, outh);
  k_poolw  <<<dim3(32, 16), 256, 0, stream>>>(u_g, mstats, rowstats, pooled);
  k_fc     <<<dim3(8, 64),  256, 0, stream>>>(outh, wfcb, fcout);
  k_ln     <<<dim3(4096),   256, 0, stream>>>(fcout, q, gamma, beta, out);
}

// Round 12
// 507.259 us; speedup vs baseline: 1.1947x; 1.1947x over previous
//
#include <hip/hip_runtime.h>
#include <cstddef>
#include <cstdint>

// ---------------- problem constants ----------------
#define ALPHA_C 7.7550531393693407f   // -log(0.001/7*3)
constexpr int BB = 2;      // batch
constexpr int LL = 2048;   // seq len
constexpr int HH = 8;      // heads
constexpr size_t OUT0  = (size_t)BB * LL * 512;          // output 0 floats
constexpr size_t PLANE = (size_t)BB * HH * LL * 64;      // per-head-major plane elems
constexpr size_t XN    = (size_t)BB * LL * 512;          // X plane elems (4096x512)
constexpr size_t WN    = (size_t)512 * 512;              // W plane elems

typedef __attribute__((ext_vector_type(8))) short bf16x8;
typedef __attribute__((ext_vector_type(4))) short short4v;
typedef __attribute__((ext_vector_type(4))) float f32x4;

__device__ inline short f2bf(float x) {
  union { float f; unsigned u; } un; un.f = x;
  unsigned r = un.u + 0x7fffu + ((un.u >> 16) & 1u);   // RNE
  return (short)(r >> 16);
}
__device__ inline float bf2f(short s) {
  union { unsigned u; float f; } un; un.u = ((unsigned)(unsigned short)s) << 16;
  return un.f;
}
// 3-way bf16 split: x ~= h + m + l (~24 mantissa bits)
__device__ inline void split3(float x, short& h, short& m, short& l) {
  h = f2bf(x); float r = x - bf2f(h);
  m = f2bf(r); float r2 = r - bf2f(m);
  l = f2bf(r2);
}

// ---------------- K0: elementwise split3 into bf16 planes (x3 tensors) --------
__global__ __launch_bounds__(256) void k_split3x(
    const float* __restrict__ a, const float* __restrict__ b, const float* __restrict__ c,
    short* __restrict__ da, short* __restrict__ db, short* __restrict__ dc, size_t n)
{
  size_t i = ((size_t)blockIdx.x * 256 + threadIdx.x) * 4;
  if (i >= n) return;
  const float* srcs[3] = {a, b, c};
  short* dsts[3] = {da, db, dc};
  #pragma unroll
  for (int s = 0; s < 3; ++s) {
    float4 x = *(const float4*)&srcs[s][i];
    short4v h, m, l;
    short th, tm, tl;
    split3(x.x, th, tm, tl); h[0] = th; m[0] = tm; l[0] = tl;
    split3(x.y, th, tm, tl); h[1] = th; m[1] = tm; l[1] = tl;
    split3(x.z, th, tm, tl); h[2] = th; m[2] = tm; l[2] = tl;
    split3(x.w, th, tm, tl); h[3] = th; m[3] = tm; l[3] = tl;
    *(short4v*)&dsts[s][i]         = h;
    *(short4v*)&dsts[s][n + i]     = m;
    *(short4v*)&dsts[s][2 * n + i] = l;
  }
}

// ---------------- K0c: fp32 -> bf16 convert (w_fc) ----------------
__global__ __launch_bounds__(256) void k_cvtbf(
    const float* __restrict__ src, short* __restrict__ dst, size_t n)
{
  size_t i = ((size_t)blockIdx.x * 256 + threadIdx.x) * 8;
  if (i >= n) return;
  float4 a = *(const float4*)&src[i];
  float4 b = *(const float4*)&src[i + 4];
  bf16x8 o;
  o[0] = f2bf(a.x); o[1] = f2bf(a.y); o[2] = f2bf(a.z); o[3] = f2bf(a.w);
  o[4] = f2bf(b.x); o[5] = f2bf(b.y); o[6] = f2bf(b.z); o[7] = f2bf(b.w);
  *(bf16x8*)&dst[i] = o;
}

// ---------------- K0b: 3-tap avg-pool of V^T along l (zero-padded) ----------------
__global__ __launch_bounds__(256) void k_vavg(
    const short* __restrict__ vt, short* __restrict__ vavgt)
{
  const size_t row = blockIdx.x;           // 1024 rows of LL
  const short* src = vt + row * LL;
  short* dst = vavgt + row * LL;
  const int c0 = threadIdx.x * 8;
  bf16x8 x = *(const bf16x8*)&src[c0];
  float xf[10];
  xf[0] = (c0 > 0) ? bf2f(src[c0 - 1]) : 0.f;
  #pragma unroll
  for (int i = 0; i < 8; ++i) xf[i + 1] = bf2f(x[i]);
  xf[9] = (c0 + 8 < LL) ? bf2f(src[c0 + 8]) : 0.f;
  bf16x8 o;
  #pragma unroll
  for (int i = 0; i < 8; ++i) o[i] = f2bf((xf[i] + xf[i + 1] + xf[i + 2]) * (1.0f / 3.0f));
  *(bf16x8*)&dst[c0] = o;
}

// ---------------- K1: QKV projection — 6-term split bf16 MFMA ----------------
__global__ __launch_bounds__(256) void k_proj(
    const short* __restrict__ xq, const short* __restrict__ xk, const short* __restrict__ xv,
    const short* __restrict__ wq3, const short* __restrict__ wk3, const short* __restrict__ wv3,
    short* __restrict__ qs, short* __restrict__ ks, short* __restrict__ vt)
{
  const int bx  = blockIdx.x;
  const int sel = bx >> 3;
  const int n0  = (bx & 7) * 64;
  const int m0  = blockIdx.y * 64;
  const short* X = sel == 0 ? xq  : (sel == 1 ? xk  : xv);
  const short* W = sel == 0 ? wq3 : (sel == 1 ? wk3 : wv3);

  __shared__ short Xs[3][64 * 72];
  __shared__ short Ws[3][64 * 72];
  const int tid = threadIdx.x;
  const int lane = tid & 63, w = tid >> 6;
  const int quad = lane >> 4, l15 = lane & 15, colg = l15;
  const int sr8 = tid >> 3, sc8 = (tid & 7) * 8;

  f32x4 acc[4];
  #pragma unroll
  for (int t = 0; t < 4; ++t) { acc[t][0]=0.f; acc[t][1]=0.f; acc[t][2]=0.f; acc[t][3]=0.f; }

  for (int kt = 0; kt < 8; ++kt) {
    const int k0 = kt * 64;
    #pragma unroll
    for (int p = 0; p < 3; ++p) {
      #pragma unroll
      for (int it = 0; it < 2; ++it) {
        int r = it * 32 + sr8;
        *(bf16x8*)&Xs[p][r * 72 + sc8] = *(const bf16x8*)&X[p * XN + (size_t)(m0 + r) * 512 + k0 + sc8];
        *(bf16x8*)&Ws[p][r * 72 + sc8] = *(const bf16x8*)&W[p * WN + (size_t)(n0 + r) * 512 + k0 + sc8];
      }
    }
    __syncthreads();
    #pragma unroll
    for (int ch = 0; ch < 2; ++ch) {
      const int ka = (quad << 3) + ch * 32;
      const int ar = (w * 16 + l15) * 72 + ka;
      bf16x8 ah = *(const bf16x8*)&Xs[0][ar];
      bf16x8 am = *(const bf16x8*)&Xs[1][ar];
      bf16x8 al = *(const bf16x8*)&Xs[2][ar];
      #pragma unroll
      for (int t = 0; t < 4; ++t) {
        const int br = (t * 16 + l15) * 72 + ka;
        bf16x8 bh_ = *(const bf16x8*)&Ws[0][br];
        bf16x8 bm_ = *(const bf16x8*)&Ws[1][br];
        bf16x8 bl_ = *(const bf16x8*)&Ws[2][br];
        acc[t] = __builtin_amdgcn_mfma_f32_16x16x32_bf16(ah, bh_, acc[t], 0, 0, 0);
        acc[t] = __builtin_amdgcn_mfma_f32_16x16x32_bf16(ah, bm_, acc[t], 0, 0, 0);
        acc[t] = __builtin_amdgcn_mfma_f32_16x16x32_bf16(am, bh_, acc[t], 0, 0, 0);
        acc[t] = __builtin_amdgcn_mfma_f32_16x16x32_bf16(ah, bl_, acc[t], 0, 0, 0);
        acc[t] = __builtin_amdgcn_mfma_f32_16x16x32_bf16(al, bh_, acc[t], 0, 0, 0);
        acc[t] = __builtin_amdgcn_mfma_f32_16x16x32_bf16(am, bm_, acc[t], 0, 0, 0);
      }
    }
    __syncthreads();
  }

  if (sel < 2) {
    short* Y = sel == 0 ? qs : ks;
    #pragma unroll
    for (int t = 0; t < 4; ++t) {
      const int e = n0 + t * 16 + colg, h = e >> 6, dk = e & 63;
      #pragma unroll
      for (int r = 0; r < 4; ++r) {
        const int m = m0 + w * 16 + quad * 4 + r;
        const int b = m >> 11, l = m & 2047;
        size_t base = ((size_t)(b * HH + h) * LL + l) * 64 + dk;
        short hh, mm, ll; split3(acc[t][r], hh, mm, ll);
        Y[base] = hh; Y[PLANE + base] = mm; Y[2 * PLANE + base] = ll;
      }
    }
  } else {
    const int b  = m0 >> 11;
    const int l0 = (m0 & 2047) + w * 16 + quad * 4;
    #pragma unroll
    for (int t = 0; t < 4; ++t) {
      const int e = n0 + t * 16 + colg, h = e >> 6, dk = e & 63;
      short4v s;
      #pragma unroll
      for (int r = 0; r < 4; ++r) s[r] = f2bf(acc[t][r]);
      *(short4v*)&vt[(((size_t)b * HH + h) * 64 + dk) * LL + l0] = s;
    }
  }
}

// ---------------- K2 (pass A): flash stats, j-split x2 — partial (M, S) --------------
// grid (32 i-tiles of 64 rows, 2 j-halves, 16 bh). Q in regs; K reg-prefetched.
__global__ __launch_bounds__(256) void k_stats(
    const short* __restrict__ qs, const short* __restrict__ ks,
    float* __restrict__ statspart)
{
  const int i0 = blockIdx.x * 64;
  const int jh = blockIdx.y;           // 0/1: j-tiles [jh*16, jh*16+16)
  const int bh = blockIdx.z;
  __shared__ short Ks[3][64 * 72];
  const int tid = threadIdx.x;
  const int lane = tid & 63, w = tid >> 6;
  const int quad = lane >> 4, colg = lane & 15, l15 = lane & 15;
  const int sr8 = tid >> 3, sc8 = (tid & 7) * 8;

  bf16x8 qf[3][2];
  {
    const size_t qoff = ((size_t)bh * LL + i0 + w * 16 + l15) * 64 + (quad << 3);
    #pragma unroll
    for (int p = 0; p < 3; ++p)
      #pragma unroll
      for (int ch = 0; ch < 2; ++ch)
        qf[p][ch] = *(const bf16x8*)&qs[p * PLANE + qoff + ch * 32];
  }

  const int jt0 = jh * 16;
  const short* kbase = ks + (size_t)bh * LL * 64;
  #pragma unroll
  for (int p = 0; p < 3; ++p)
    #pragma unroll
    for (int it = 0; it < 2; ++it) {
      int r = it * 32 + sr8;
      *(bf16x8*)&Ks[p][r * 72 + sc8] =
          *(const bf16x8*)&kbase[p * PLANE + ((size_t)jt0 * 64 + r) * 64 + sc8];
    }
  __syncthreads();

  float M[4], S[4];
  #pragma unroll
  for (int r = 0; r < 4; ++r) { M[r] = -3.0e38f; S[r] = 0.f; }

  for (int jj = 0; jj < 16; ++jj) {
    const int jt = jt0 + jj;
    const int j0 = jt * 64;
    bf16x8 kreg[3][2];
    if (jj + 1 < 16) {
      #pragma unroll
      for (int p = 0; p < 3; ++p)
        #pragma unroll
        for (int it = 0; it < 2; ++it) {
          int r = it * 32 + sr8;
          kreg[p][it] = *(const bf16x8*)&kbase[p * PLANE + ((size_t)(jt + 1) * 64 + r) * 64 + sc8];
        }
    }

    f32x4 acc[4];
    #pragma unroll
    for (int t = 0; t < 4; ++t) { acc[t][0]=0.f; acc[t][1]=0.f; acc[t][2]=0.f; acc[t][3]=0.f; }
    #pragma unroll
    for (int ch = 0; ch < 2; ++ch) {
      const int ka = (quad << 3) + ch * 32;
      #pragma unroll
      for (int t = 0; t < 4; ++t) {
        const int br = (t * 16 + l15) * 72 + ka;
        bf16x8 bh_ = *(const bf16x8*)&Ks[0][br];
        bf16x8 bm_ = *(const bf16x8*)&Ks[1][br];
        bf16x8 bl_ = *(const bf16x8*)&Ks[2][br];
        acc[t] = __builtin_amdgcn_mfma_f32_16x16x32_bf16(qf[0][ch], bh_, acc[t], 0, 0, 0);
        acc[t] = __builtin_amdgcn_mfma_f32_16x16x32_bf16(qf[0][ch], bm_, acc[t], 0, 0, 0);
        acc[t] = __builtin_amdgcn_mfma_f32_16x16x32_bf16(qf[1][ch], bh_, acc[t], 0, 0, 0);
        acc[t] = __builtin_amdgcn_mfma_f32_16x16x32_bf16(qf[0][ch], bl_, acc[t], 0, 0, 0);
        acc[t] = __builtin_amdgcn_mfma_f32_16x16x32_bf16(qf[2][ch], bh_, acc[t], 0, 0, 0);
        acc[t] = __builtin_amdgcn_mfma_f32_16x16x32_bf16(qf[1][ch], bm_, acc[t], 0, 0, 0);
      }
    }

    // lane-local online update
    #pragma unroll
    for (int r = 0; r < 4; ++r) {
      const int irow = i0 + w * 16 + quad * 4 + r;
      float e0 = -ALPHA_C * (float)(j0 +  0 + colg - irow) * (acc[0][r] * 0.125f);
      float e1 = -ALPHA_C * (float)(j0 + 16 + colg - irow) * (acc[1][r] * 0.125f);
      float e2 = -ALPHA_C * (float)(j0 + 32 + colg - irow) * (acc[2][r] * 0.125f);
      float e3 = -ALPHA_C * (float)(j0 + 48 + colg - irow) * (acc[3][r] * 0.125f);
      float mx = fmaxf(fmaxf(e0, e1), fmaxf(e2, e3));
      float nM = fmaxf(M[r], mx);
      S[r] = S[r] * __expf(M[r] - nM)
           + __expf(e0 - nM) + __expf(e1 - nM) + __expf(e2 - nM) + __expf(e3 - nM);
      M[r] = nM;
    }

    __syncthreads();
    if (jj + 1 < 16) {
      #pragma unroll
      for (int p = 0; p < 3; ++p)
        #pragma unroll
        for (int it = 0; it < 2; ++it) {
          int r = it * 32 + sr8;
          *(bf16x8*)&Ks[p][r * 72 + sc8] = kreg[p][it];
        }
    }
    __syncthreads();
  }

  // cross-lane merge (16 colg lanes)
  #pragma unroll
  for (int r = 0; r < 4; ++r) {
    float M_ = M[r], S_ = S[r];
    #pragma unroll
    for (int d = 1; d < 16; d <<= 1) {
      float Mo = __shfl_xor(M_, d);
      float So = __shfl_xor(S_, d);
      float nM = fmaxf(M_, Mo);
      S_ = S_ * __expf(M_ - nM) + So * __expf(Mo - nM);
      M_ = nM;
    }
    if (colg == 0) {
      int irow = i0 + w * 16 + quad * 4 + r;
      size_t idx = (((size_t)jh * 16 + bh) * LL + irow) * 2;
      statspart[idx] = M_; statspart[idx + 1] = S_;
    }
  }
}

// ---------------- K2b: merge the two j-half partials -> rowstats ----------------
__global__ __launch_bounds__(256) void k_mergestats(
    const float* __restrict__ statspart, float* __restrict__ rowstats)
{
  const size_t row = (size_t)blockIdx.x * 256 + threadIdx.x;   // bh*LL + irow, < 32768
  float2 a = *(const float2*)&statspart[row * 2];
  float2 b = *(const float2*)&statspart[(size_t)16 * LL * 2 + row * 2];
  float nM = fmaxf(a.x, b.x);
  float S = a.y * __expf(a.x - nM) + b.y * __expf(b.x - nM);
  rowstats[row * 2] = nM; rowstats[row * 2 + 1] = S;
}

// ---------------- K3 (pass B): QK -> p -> {vector pool write, PV w/ pooled-V} --------
// grid (32 i-tiles of 64 rows, 16 bh). Wave = 16 rows x 64 cols. 2 barriers/iter.
__global__ __launch_bounds__(256) void k_pool_pv(
    const short* __restrict__ qs, const short* __restrict__ ks,
    const short* __restrict__ vavgt, const float* __restrict__ rowstats,
    float* __restrict__ pooled, short* __restrict__ outh)
{
  const int i0 = blockIdx.x * 64;
  const int bh = blockIdx.y;
  const int b = bh >> 3, h = bh & 7;
  float*       Pg = pooled + (size_t)bh * LL * LL;
  const short* Vt = vavgt + (size_t)bh * 64 * LL;
  const short* kbase = ks + (size_t)bh * LL * 64;

  __shared__ short Ks[3][64 * 72];     // 27.6 KB
  __shared__ short Vsm[64 * 72];       // 9.2 KB
  __shared__ short Pa[2][64 * 72];     // 18.4 KB raw p (bf16), 2-slot
  __shared__ float Mrow[64], invSr[64], lhalo[64];

  const int tid = threadIdx.x;
  const int lane = tid & 63, w = tid >> 6;
  const int quad = lane >> 4, colg = lane & 15, l15 = lane & 15;
  const int sr8 = tid >> 3, sc8 = (tid & 7) * 8;

  bf16x8 qf[3][2];
  {
    const size_t qoff = ((size_t)bh * LL + i0 + w * 16 + l15) * 64 + (quad << 3);
    #pragma unroll
    for (int p = 0; p < 3; ++p)
      #pragma unroll
      for (int ch = 0; ch < 2; ++ch)
        qf[p][ch] = *(const bf16x8*)&qs[p * PLANE + qoff + ch * 32];
  }
  if (tid < 64) {
    float2 ms = *(const float2*)&rowstats[((size_t)bh * LL + i0 + tid) * 2];
    Mrow[tid] = ms.x; invSr[tid] = 1.0f / ms.y; lhalo[tid] = 0.f;
  }

  // prestage K(0)
  #pragma unroll
  for (int p = 0; p < 3; ++p)
    #pragma unroll
    for (int it = 0; it < 2; ++it) {
      int r = it * 32 + sr8;
      *(bf16x8*)&Ks[p][r * 72 + sc8] = *(const bf16x8*)&kbase[p * PLANE + (size_t)r * 64 + sc8];
    }
  __syncthreads();

  f32x4 pv[4];
  #pragma unroll
  for (int t = 0; t < 4; ++t) { pv[t][0]=0.f; pv[t][1]=0.f; pv[t][2]=0.f; pv[t][3]=0.f; }

  for (int jt = 0; jt <= 32; ++jt) {
    // ---- phase A: QK(jt) -> raw p -> Pa[jt&1]; stage Vavg(jt-1) ----
    if (jt < 32) {
      const int j0 = jt * 64;
      f32x4 acc[4];
      #pragma unroll
      for (int t = 0; t < 4; ++t) { acc[t][0]=0.f; acc[t][1]=0.f; acc[t][2]=0.f; acc[t][3]=0.f; }
      #pragma unroll
      for (int ch = 0; ch < 2; ++ch) {
        const int ka = (quad << 3) + ch * 32;
        #pragma unroll
        for (int t = 0; t < 4; ++t) {
          const int br = (t * 16 + l15) * 72 + ka;
          bf16x8 bh_ = *(const bf16x8*)&Ks[0][br];
          bf16x8 bm_ = *(const bf16x8*)&Ks[1][br];
          bf16x8 bl_ = *(const bf16x8*)&Ks[2][br];
          acc[t] = __builtin_amdgcn_mfma_f32_16x16x32_bf16(qf[0][ch], bh_, acc[t], 0, 0, 0);
          acc[t] = __builtin_amdgcn_mfma_f32_16x16x32_bf16(qf[0][ch], bm_, acc[t], 0, 0, 0);
          acc[t] = __builtin_amdgcn_mfma_f32_16x16x32_bf16(qf[1][ch], bh_, acc[t], 0, 0, 0);
          acc[t] = __builtin_amdgcn_mfma_f32_16x16x32_bf16(qf[0][ch], bl_, acc[t], 0, 0, 0);
          acc[t] = __builtin_amdgcn_mfma_f32_16x16x32_bf16(qf[2][ch], bh_, acc[t], 0, 0, 0);
          acc[t] = __builtin_amdgcn_mfma_f32_16x16x32_bf16(qf[1][ch], bm_, acc[t], 0, 0, 0);
        }
      }
      short* Pc = Pa[jt & 1];
      #pragma unroll
      for (int r = 0; r < 4; ++r) {
        const int row = w * 16 + quad * 4 + r;
        const int irow = i0 + row;
        const float Mr = Mrow[row], iS = invSr[row];
        #pragma unroll
        for (int t = 0; t < 4; ++t) {
          int jl = t * 16 + colg;
          float e = -ALPHA_C * (float)(j0 + jl - irow) * (acc[t][r] * 0.125f);
          Pc[row * 72 + jl] = f2bf(__expf(e - Mr) * iS);
        }
      }
    }
    if (jt >= 1) {
      #pragma unroll
      for (int it = 0; it < 2; ++it) {
        int d = it * 32 + sr8;
        *(bf16x8*)&Vsm[d * 72 + sc8] = *(const bf16x8*)&Vt[(size_t)d * LL + (jt - 1) * 64 + sc8];
      }
    }
    __syncthreads();

    // ---- phase B: vector pool-write(jt-1); PV(jt-1); stage K(jt+1) ----
    if (jt >= 1) {
      const short* Pp = Pa[(jt - 1) & 1];
      const short* Pn = Pa[jt & 1];
      #pragma unroll
      for (int u = 0; u < 2; ++u) {
        const int row = (u == 0) ? (tid >> 3) : (tid >> 3) + 32;
        const int c0 = (tid & 7) * 8;
        bf16x8 x = *(const bf16x8*)&Pp[row * 72 + c0];
        float xf[8];
        #pragma unroll
        for (int i = 0; i < 8; ++i) xf[i] = bf2f(x[i]);
        float lft = (c0 == 0)  ? lhalo[row] : bf2f(Pp[row * 72 + c0 - 1]);
        float rgt = (c0 == 56) ? ((jt < 32) ? bf2f(Pn[row * 72]) : 0.f)
                               : bf2f(Pp[row * 72 + c0 + 8]);
        f32x4 o0, o1;
        o0[0] = (lft   + xf[0] + xf[1]) * (1.0f/3.0f);
        o0[1] = (xf[0] + xf[1] + xf[2]) * (1.0f/3.0f);
        o0[2] = (xf[1] + xf[2] + xf[3]) * (1.0f/3.0f);
        o0[3] = (xf[2] + xf[3] + xf[4]) * (1.0f/3.0f);
        o1[0] = (xf[3] + xf[4] + xf[5]) * (1.0f/3.0f);
        o1[1] = (xf[4] + xf[5] + xf[6]) * (1.0f/3.0f);
        o1[2] = (xf[5] + xf[6] + xf[7]) * (1.0f/3.0f);
        o1[3] = (xf[6] + xf[7] + rgt  ) * (1.0f/3.0f);
        float* dst = &Pg[(size_t)(i0 + row) * LL + (jt - 1) * 64 + c0];
        __builtin_nontemporal_store(o0, (f32x4*)dst);
        __builtin_nontemporal_store(o1, (f32x4*)(dst + 4));
        if (c0 == 56) lhalo[row] = xf[7];
      }
      #pragma unroll
      for (int ch = 0; ch < 2; ++ch) {
        const int ka = (quad << 3) + ch * 32;
        bf16x8 af = *(const bf16x8*)&Pp[(w * 16 + l15) * 72 + ka];
        #pragma unroll
        for (int t = 0; t < 4; ++t) {
          bf16x8 bfv = *(const bf16x8*)&Vsm[(t * 16 + l15) * 72 + ka];
          pv[t] = __builtin_amdgcn_mfma_f32_16x16x32_bf16(af, bfv, pv[t], 0, 0, 0);
        }
      }
    }
    if (jt + 1 < 32) {
      #pragma unroll
      for (int p = 0; p < 3; ++p)
        #pragma unroll
        for (int it = 0; it < 2; ++it) {
          int r = it * 32 + sr8;
          *(bf16x8*)&Ks[p][r * 72 + sc8] =
              *(const bf16x8*)&kbase[p * PLANE + ((size_t)(jt + 1) * 64 + r) * 64 + sc8];
        }
    }
    __syncthreads();
  }

  #pragma unroll
  for (int t = 0; t < 4; ++t)
    #pragma unroll
    for (int r = 0; r < 4; ++r) {
      int i = i0 + w * 16 + quad * 4 + r;
      int d = t * 16 + colg;
      outh[((size_t)b * LL + i) * 512 + h * 64 + d] = f2bf(pv[t][r]);
    }
}

// ---------------- K4: fc = out_h @ w_fc^T  (pure bf16 MFMA, copy staging) ----------
__global__ __launch_bounds__(256) void k_fc(
    const short* __restrict__ outh, const short* __restrict__ wfcb, float* __restrict__ fcout)
{
  const int n0 = blockIdx.x * 64;
  const int m0 = blockIdx.y * 64;
  __shared__ short Asm[64 * 72];
  __shared__ short Bsm[64 * 72];
  const int tid = threadIdx.x;
  const int lane = tid & 63, w = tid >> 6;
  const int sr8 = tid >> 3, sc8 = (tid & 7) * 8;

  f32x4 acc[4];
  #pragma unroll
  for (int t = 0; t < 4; ++t) { acc[t][0]=0.f; acc[t][1]=0.f; acc[t][2]=0.f; acc[t][3]=0.f; }

  for (int k0 = 0; k0 < 512; k0 += 64) {
    #pragma unroll
    for (int it = 0; it < 2; ++it) {
      int r = it * 32 + sr8;
      *(bf16x8*)&Asm[r * 72 + sc8] = *(const bf16x8*)&outh[(size_t)(m0 + r) * 512 + k0 + sc8];
      *(bf16x8*)&Bsm[r * 72 + sc8] = *(const bf16x8*)&wfcb[(size_t)(n0 + r) * 512 + k0 + sc8];
    }
    __syncthreads();
    #pragma unroll
    for (int ch = 0; ch < 2; ++ch) {
      const int ka = ((lane >> 4) << 3) + ch * 32;
      bf16x8 af = *(const bf16x8*)&Asm[(w * 16 + (lane & 15)) * 72 + ka];
      #pragma unroll
      for (int t = 0; t < 4; ++t) {
        bf16x8 bfv = *(const bf16x8*)&Bsm[(t * 16 + (lane & 15)) * 72 + ka];
        acc[t] = __builtin_amdgcn_mfma_f32_16x16x32_bf16(af, bfv, acc[t], 0, 0, 0);
      }
    }
    __syncthreads();
  }
  const int q4 = lane >> 4, colg = lane & 15;
  #pragma unroll
  for (int t = 0; t < 4; ++t)
    #pragma unroll
    for (int r = 0; r < 4; ++r) {
      int m = m0 + w * 16 + q4 * 4 + r;
      fcout[(size_t)m * 512 + n0 + t * 16 + colg] = acc[t][r];
    }
}

// ---------------- K5: residual + LayerNorm ----------------
__global__ __launch_bounds__(256) void k_ln(
    const float* __restrict__ fcout, const float* __restrict__ resid,
    const float* __restrict__ gamma, const float* __restrict__ beta,
    float* __restrict__ out)
{
  const size_t row = blockIdx.x;
  const int tid = threadIdx.x;
  __shared__ float red[256];

  float x0 = fcout[row * 512 + tid]       + resid[row * 512 + tid];
  float x1 = fcout[row * 512 + 256 + tid] + resid[row * 512 + 256 + tid];

  red[tid] = x0 + x1; __syncthreads();
  for (int off = 128; off > 0; off >>= 1) {
    if (tid < off) red[tid] += red[tid + off];
    __syncthreads();
  }
  const float mu = red[0] * (1.0f / 512.0f); __syncthreads();

  float d0 = x0 - mu, d1 = x1 - mu;
  red[tid] = d0 * d0 + d1 * d1; __syncthreads();
  for (int off = 128; off > 0; off >>= 1) {
    if (tid < off) red[tid] += red[tid + off];
    __syncthreads();
  }
  const float var = red[0] * (1.0f / 512.0f);
  const float rstd = 1.0f / sqrtf(var + 1e-6f);

  out[row * 512 + tid]       = d0 * rstd * gamma[tid]       + beta[tid];
  out[row * 512 + 256 + tid] = d1 * rstd * gamma[tid + 256] + beta[tid + 256];
}

// ---------------- launch ----------------
extern "C" void kernel_launch(void* const* d_in, const int* in_sizes, int n_in,
                              void* d_out, int out_size, void* d_ws, size_t ws_size,
                              hipStream_t stream)
{
  const float* q     = (const float*)d_in[0];
  const float* k     = (const float*)d_in[1];
  const float* v     = (const float*)d_in[2];
  const float* wq    = (const float*)d_in[3];
  const float* wk    = (const float*)d_in[4];
  const float* wv    = (const float*)d_in[5];
  const float* wfc   = (const float*)d_in[6];
  const float* gamma = (const float*)d_in[7];
  const float* beta  = (const float*)d_in[8];

  float* out    = (float*)d_out;
  float* pooled = out + OUT0;

  // workspace layout (~100 MB)
  short* xq    = (short*)d_ws;           // 3*XN each
  short* xk    = xq + 3 * XN;
  short* xv    = xk + 3 * XN;
  short* wq3   = xv + 3 * XN;            // 3*WN each
  short* wk3   = wq3 + 3 * WN;
  short* wv3   = wk3 + 3 * WN;
  short* qsp   = wv3 + 3 * WN;           // 3*PLANE
  short* ksp   = qsp + 3 * PLANE;        // 3*PLANE
  short* vt    = ksp + 3 * PLANE;        // PLANE (raw V^T)
  short* vavgt = vt + PLANE;             // PLANE (pooled V^T)
  short* wfcb  = vavgt + PLANE;          // WN bf16
  short* outh  = wfcb + WN;              // OUT0 bf16
  float* statspart = (float*)(outh + OUT0);          // 2 x 65536 f32
  float* rowstats  = statspart + 4 * (size_t)BB * HH * LL;
  float* fcout     = rowstats + 2 * (size_t)BB * HH * LL;

  k_split3x<<<dim3((unsigned)(XN / 4 / 256)), 256, 0, stream>>>(q, k, v, xq, xk, xv, XN);
  k_split3x<<<dim3((unsigned)(WN / 4 / 256)), 256, 0, stream>>>(wq, wk, wv, wq3, wk3, wv3, WN);
  k_cvtbf  <<<dim3((unsigned)(WN / 8 / 256)), 256, 0, stream>>>(wfc, wfcb, WN);
  k_proj   <<<dim3(24, 64), 256, 0, stream>>>(xq, xk, xv, wq3, wk3, wv3, qsp, ksp, vt);
  k_vavg   <<<dim3(1024),   256, 0, stream>>>(vt, vavgt);
  k_stats  <<<dim3(32, 2, 16), 256, 0, stream>>>(qsp, ksp, statspart);
  k_mergestats<<<dim3(128), 256, 0, stream>>>(statspart, rowstats);
  k_pool_pv<<<dim3(32, 16), 256, 0, stream>>>(qsp, ksp, vavgt, rowstats, pooled, outh);
  k_fc     <<<dim3(8, 64),  256, 0, stream>>>(outh, wfcb, fcout);
  k_ln     <<<dim3(4096),   256, 0, stream>>>(fcout, q, gamma, beta, out);
}